// Round 5
// baseline (247.665 us; speedup 1.0000x reference)
//
#include <hip/hip_runtime.h>
#include <hip/hip_bf16.h>

// CRF loss via associative chunked scan (MFMA layouts verified R2-R4).
// R5: gold path hoisted to a once-per-chunk vectorized gather (inner loop has
// ZERO scalar memory ops -> no lgkmcnt(0) stalls); A built one step ahead to
// fill the MFMA->VALU hazard window; 4-deep feature prefetch; unroll 2.

constexpr int BN = 1024, TN = 1024, LN = 32;
constexpr float KSHIFT = 8.5f;     // per-step factors ~e^{-2}: monotone decay
constexpr float LN2F   = 0.69314718056f;

typedef __attribute__((ext_vector_type(8)))  short bf16x8;
typedef __attribute__((ext_vector_type(16))) float f32x16;
typedef __attribute__((ext_vector_type(2)))  float f32x2;

// pack two f32 -> (bf16(a) | bf16(b)<<16) by truncation: one v_perm_b32
static __device__ __forceinline__ unsigned pktrunc(float a, float b) {
    return __builtin_amdgcn_perm(__float_as_uint(b), __float_as_uint(a), 0x07060302u);
}
// v_permlane32_swap_b32: a.row1 <-> b.row0 (register-only cross-half exchange)
#define PLSWAP(a, b) asm("v_permlane32_swap_b32 %0, %1" : "+v"(a), "+v"(b))

// ---------------- Phase 1: chunk transfer-matrix products ----------------
__global__ __launch_bounds__(256, 4) void crf_chunk(
    const float* __restrict__ feat,   // [B][T][L]
    const float* __restrict__ trans,  // [L][L]
    const int*   __restrict__ lab,    // [B][T]
    float* __restrict__ ws,           // [B*CH][32][32] log-space products
    float* __restrict__ out,          // [1] (gold subtracted here)
    int CHS)
{
    const int CH = 1 << CHS, LEN = TN >> CHS;
    const int l = threadIdx.x & 63, n = l & 31, h = l >> 5;
    const int wid = __builtin_amdgcn_readfirstlane((int)(threadIdx.x >> 6));
    const int gid = blockIdx.x * 4 + wid;            // wave id = chunk id
    const int c = gid & (CH - 1), b = gid >> CHS;

    const float* __restrict__ fb = feat + (size_t)b * TN * LN;
    const int*   __restrict__ lb = lab  + (size_t)b * TN;

    const int start = c * LEN, te = start + LEN;
    const int tm = (c == 0) ? 2 : start;   // chunk 0: t=1 folded into alpha_1

    // ---- gold path: vectorized gather, once per chunk (no in-loop scalars) ----
    {
        float gsum = 0.f;
        for (int r = 0; r < LEN; r += 64) {
            int t = start + r + l;                 // t <= te-1 by construction
            if (t >= 1) {                          // excludes only t=0 (chunk 0)
                int cur = lb[t];
                int prv = lb[t - 1];
                gsum += trans[cur * LN + prv] + fb[(size_t)t * LN + cur];
            }
        }
        #pragma unroll
        for (int s = 32; s; s >>= 1) gsum += __shfl_xor(gsum, s, 64);
        if (l == 0) atomicAdd(out, -gsum * (1.0f / (float)BN));
    }

    // A-operand constants as pairs: EA for k=8h+2r(+1), EB for k=16+8h+2r(+1)
    f32x2 EA[4], EB[4];
    #pragma unroll
    for (int r = 0; r < 4; ++r) {
        EA[r][0] = __expf(trans[n * LN + 8 * h + 2 * r]          - KSHIFT);
        EA[r][1] = __expf(trans[n * LN + 8 * h + 2 * r + 1]      - KSHIFT);
        EB[r][0] = __expf(trans[n * LN + 16 + 8 * h + 2 * r]     - KSHIFT);
        EB[r][1] = __expf(trans[n * LN + 16 + 8 * h + 2 * r + 1] - KSHIFT);
    }

    // Running product as B operand (lane -> col n, k=8h+e); init Identity.
    union BU { bf16x8 v; unsigned u[4]; } B1f, B2f;
    #pragma unroll
    for (int r = 0; r < 4; ++r) {
        int k0 = 8 * h + 2 * r, k1 = k0 + 1;
        B1f.u[r] = (k0 == n ? 0x3F80u : 0u) | ((k1 == n ? 0x3F80u : 0u) << 16);
        B2f.u[r] = (k0 + 16 == n ? 0x3F80u : 0u) | ((k1 + 16 == n ? 0x3F80u : 0u) << 16);
    }

    // ---- feature pipeline: depth 4 ----
    float fcur = fb[(size_t)tm * LN + n];
    float f1   = fb[(size_t)(tm + 1) * LN + n];
    float f2   = fb[(size_t)(tm + 2) * LN + n];
    float f3   = fb[(size_t)(tm + 3) * LN + n];

    // A(tm) built in prologue
    union BU A1, A2, A1n, A2n;
    {
        float F = __expf(fcur);
        f32x2 F2; F2[0] = F; F2[1] = F;
        #pragma unroll
        for (int r = 0; r < 4; ++r) {
            f32x2 pa = EA[r] * F2;
            f32x2 pb = EB[r] * F2;
            A1.u[r] = pktrunc(pa[0], pa[1]);
            A2.u[r] = pktrunc(pb[0], pb[1]);
        }
    }

    int sc = 0;                   // accumulated pow2 exponent (per column)
    f32x16 ZR;
    #pragma unroll
    for (int i = 0; i < 16; ++i) ZR[i] = 0.f;
    f32x16 C;

    #pragma unroll 2
    for (int t = tm; t < te; ++t) {
        // ---- step t: two chained MFMAs (K=32) ----
        C = __builtin_amdgcn_mfma_f32_32x32x16_bf16(A1.v, B1f.v, ZR, 0, 0, 0);
        C = __builtin_amdgcn_mfma_f32_32x32x16_bf16(A2.v, B2f.v, C, 0, 0, 0);

        // ---- prefetch feat[t+4] (clamped; vector load, in-order vmcnt) ----
        const int tp = (t + 4 < te) ? (t + 4) : (te - 1);
        float fl = fb[(size_t)tp * LN + n];

        // ---- build A(t+1) from f1: independent of C, fills MFMA hazard ----
        float F = __expf(f1);
        f32x2 F2; F2[0] = F; F2[1] = F;
        #pragma unroll
        for (int r = 0; r < 4; ++r) {
            f32x2 pa = EA[r] * F2;
            f32x2 pb = EB[r] * F2;
            A1n.u[r] = pktrunc(pa[0], pa[1]);
            A2n.u[r] = pktrunc(pb[0], pb[1]);
        }

        // ---- per-column pow2 rescale every 16 steps (exact; diag commutes) ----
        if ((t & 15) == 15) {
            float cm = C[0];
            #pragma unroll
            for (int i = 1; i < 16; ++i) cm = fmaxf(cm, C[i]);
            unsigned ca = __float_as_uint(cm), cb = ca;
            PLSWAP(ca, cb);                       // column consensus across halves
            cm = fmaxf(__uint_as_float(ca), __uint_as_float(cb));
            cm = fmaxf(cm, 1e-30f);
            int ex; frexpf(cm, &ex);
            sc += ex;
            #pragma unroll
            for (int i = 0; i < 16; ++i) C[i] = ldexpf(C[i], -ex);
        }

        // ---- C (col=l&31, row=(r&3)+8*(r>>2)+4h) -> next-step B operands ----
        unsigned PK[8];
        #pragma unroll
        for (int r = 0; r < 8; ++r) PK[r] = pktrunc(C[2 * r], C[2 * r + 1]);
        PLSWAP(PK[0], PK[2]);  PLSWAP(PK[1], PK[3]);
        PLSWAP(PK[4], PK[6]);  PLSWAP(PK[5], PK[7]);
        B1f.u[0] = PK[0]; B1f.u[1] = PK[1]; B1f.u[2] = PK[2]; B1f.u[3] = PK[3];
        B2f.u[0] = PK[4]; B2f.u[1] = PK[5]; B2f.u[2] = PK[6]; B2f.u[3] = PK[7];

        // ---- rotate pipelines ----
        A1 = A1n; A2 = A2n;
        f1 = f2; f2 = f3; f3 = fl;
    }

    // write log-space chunk matrix: log(true) = ln(C) + sc*ln2 + K*len
    const float add = KSHIFT * (float)(te - tm) + (float)sc * LN2F;
    float* __restrict__ w = ws + ((size_t)gid << 10);
    #pragma unroll
    for (int r = 0; r < 16; ++r) {
        int row = (r & 3) + 8 * (r >> 2) + 4 * h;
        float v = C[r];
        w[row * LN + n] = (v > 0.f) ? (__logf(v) + add) : -10000.0f;
    }
}

// ---------------- Phase 2: log-space combine + final lse ----------------
__global__ __launch_bounds__(64) void crf_combine(
    const float* __restrict__ trans,
    const float* __restrict__ feat,
    const float* __restrict__ ws,
    float* __restrict__ out,
    int CHS)
{
    const int CH = 1 << CHS;
    const int l = threadIdx.x & 63, i = l & 31;
    const int seq = blockIdx.x * 2 + (l >> 5);
    const int bb = (l & 32) << 2;   // group-local bpermute base

    // alpha_1[i] = trans[i][0] + feat[1][i]  (exact)
    float alpha = trans[i * LN] + feat[(size_t)seq * TN * LN + LN + i];
    const float* __restrict__ wsb = ws + ((size_t)seq << (10 + CHS));

    for (int c = 0; c < CH; ++c) {
        const float4* Mr = (const float4*)(wsb + (c << 10) + i * LN);
        float vv[32];
        #pragma unroll
        for (int q = 0; q < 8; ++q) {
            float4 m4 = Mr[q];
            vv[4 * q + 0] = m4.x; vv[4 * q + 1] = m4.y;
            vv[4 * q + 2] = m4.z; vv[4 * q + 3] = m4.w;
        }
        float mx = -1e30f;
        #pragma unroll
        for (int j = 0; j < 32; ++j) {
            int r = __builtin_amdgcn_ds_bpermute(bb + (j << 2), __float_as_int(alpha));
            vv[j] += __int_as_float(r);
            mx = fmaxf(mx, vv[j]);
        }
        float s = 0.f;
        #pragma unroll
        for (int j = 0; j < 32; ++j) s += __expf(vv[j] - mx);
        alpha = mx + __logf(s);
    }

    // forward score = lse over 32 states
    float m = alpha;
    #pragma unroll
    for (int s = 16; s; s >>= 1) m = fmaxf(m, __shfl_xor(m, s, 32));
    float es = __expf(alpha - m);
    #pragma unroll
    for (int s = 16; s; s >>= 1) es += __shfl_xor(es, s, 32);
    float fs = m + __logf(es);

    if (i == 0) atomicAdd(out, fs * (1.0f / (float)BN));
}

extern "C" void kernel_launch(void* const* d_in, const int* in_sizes, int n_in,
                              void* d_out, int out_size, void* d_ws, size_t ws_size,
                              hipStream_t stream) {
    const float* features    = (const float*)d_in[0];
    const float* transitions = (const float*)d_in[1];
    const int*   labels      = (const int*)d_in[2];
    float* out = (float*)d_out;
    float* ws  = (float*)d_ws;

    int CHS = 3;
    while (CHS > 0 && ws_size < (((size_t)BN << CHS) * (LN * LN * 4))) --CHS;
    const int CH = 1 << CHS;

    hipMemsetAsync(out, 0, sizeof(float), stream);
    crf_chunk<<<dim3((BN * CH) / 4), dim3(256), 0, stream>>>(
        features, transitions, labels, ws, out, CHS);
    crf_combine<<<dim3(BN / 2), dim3(64), 0, stream>>>(
        transitions, features, ws, out, CHS);
}

// Round 6
// 225.483 us; speedup vs baseline: 1.0984x; 1.0984x over previous
//
#include <hip/hip_runtime.h>
#include <hip/hip_bf16.h>

// CRF loss via associative chunked scan (MFMA layouts verified R2-R5).
// R6: register-class pins (asm "+v") on C/A/B/ZR to force arch-VGPR
// allocation of the MFMA chain -- R3-R5 counters (VGPR_Count=28-32 with ~90
// live values) show the compiler was routing operands through AGPRs, putting
// v_accvgpr_read/write moves on the serial step chain. Unroll 4, hoisted
// gold gather, zero in-loop scalar memory ops.

constexpr int BN = 1024, TN = 1024, LN = 32;
constexpr float KSHIFT = 8.5f;     // per-step factors ~e^{-2}: monotone decay
constexpr float LN2F   = 0.69314718056f;

typedef __attribute__((ext_vector_type(8)))  short bf16x8;
typedef __attribute__((ext_vector_type(16))) float f32x16;
typedef __attribute__((ext_vector_type(2)))  float f32x2;

// pack two f32 -> (bf16(a) | bf16(b)<<16) by truncation: one v_perm_b32
static __device__ __forceinline__ unsigned pktrunc(float a, float b) {
    return __builtin_amdgcn_perm(__float_as_uint(b), __float_as_uint(a), 0x07060302u);
}
// v_permlane32_swap_b32: a.row1 <-> b.row0 (register-only cross-half exchange)
#define PLSWAP(a, b) asm("v_permlane32_swap_b32 %0, %1" : "+v"(a), "+v"(b))
// register-class pin: force live range into arch VGPRs (no code emitted)
#define PIN_V(x) asm("" : "+v"(x))

// ---------------- Phase 1: chunk transfer-matrix products ----------------
__global__ __launch_bounds__(256, 4) void crf_chunk(
    const float* __restrict__ feat,   // [B][T][L]
    const float* __restrict__ trans,  // [L][L]
    const int*   __restrict__ lab,    // [B][T]
    float* __restrict__ ws,           // [B*CH][32][32] log-space products
    float* __restrict__ out,          // [1] (gold subtracted here)
    int CHS)
{
    const int CH = 1 << CHS, LEN = TN >> CHS;
    const int l = threadIdx.x & 63, n = l & 31, h = l >> 5;
    const int wid = __builtin_amdgcn_readfirstlane((int)(threadIdx.x >> 6));
    const int gid = blockIdx.x * 4 + wid;            // wave id = chunk id
    const int c = gid & (CH - 1), b = gid >> CHS;

    const float* __restrict__ fb = feat + (size_t)b * TN * LN;
    const int*   __restrict__ lb = lab  + (size_t)b * TN;

    const int start = c * LEN, te = start + LEN;
    const int tm = (c == 0) ? 2 : start;   // chunk 0: t=1 folded into alpha_1

    // ---- gold path: vectorized gather, once per chunk (no in-loop scalars) ----
    {
        float gsum = 0.f;
        for (int r = 0; r < LEN; r += 64) {
            int t = start + r + l;                 // t <= te-1 by construction
            if (t >= 1) {                          // excludes only t=0 (chunk 0)
                int cur = lb[t];
                int prv = lb[t - 1];
                gsum += trans[cur * LN + prv] + fb[(size_t)t * LN + cur];
            }
        }
        #pragma unroll
        for (int s = 32; s; s >>= 1) gsum += __shfl_xor(gsum, s, 64);
        if (l == 0) atomicAdd(out, -gsum * (1.0f / (float)BN));
    }

    // A-operand constants as pairs: EA for k=8h+2r(+1), EB for k=16+8h+2r(+1)
    f32x2 EA[4], EB[4];
    #pragma unroll
    for (int r = 0; r < 4; ++r) {
        EA[r][0] = __expf(trans[n * LN + 8 * h + 2 * r]          - KSHIFT);
        EA[r][1] = __expf(trans[n * LN + 8 * h + 2 * r + 1]      - KSHIFT);
        EB[r][0] = __expf(trans[n * LN + 16 + 8 * h + 2 * r]     - KSHIFT);
        EB[r][1] = __expf(trans[n * LN + 16 + 8 * h + 2 * r + 1] - KSHIFT);
    }

    // Running product as B operand (lane -> col n, k=8h+e); init Identity.
    union BU { bf16x8 v; unsigned u[4]; } B1f, B2f;
    #pragma unroll
    for (int r = 0; r < 4; ++r) {
        int k0 = 8 * h + 2 * r, k1 = k0 + 1;
        B1f.u[r] = (k0 == n ? 0x3F80u : 0u) | ((k1 == n ? 0x3F80u : 0u) << 16);
        B2f.u[r] = (k0 + 16 == n ? 0x3F80u : 0u) | ((k1 + 16 == n ? 0x3F80u : 0u) << 16);
    }
    PIN_V(B1f.v); PIN_V(B2f.v);

    // ---- feature pipeline: depth 4 ----
    float f0 = fb[(size_t)tm * LN + n];
    float f1 = fb[(size_t)(tm + 1) * LN + n];
    float f2 = fb[(size_t)(tm + 2) * LN + n];
    float f3 = fb[(size_t)(tm + 3) * LN + n];

    // A(tm) built in prologue
    union BU A1, A2, A1n, A2n;
    {
        float F = __expf(f0);
        f32x2 F2; F2[0] = F; F2[1] = F;
        #pragma unroll
        for (int r = 0; r < 4; ++r) {
            f32x2 pa = EA[r] * F2;
            f32x2 pb = EB[r] * F2;
            A1.u[r] = pktrunc(pa[0], pa[1]);
            A2.u[r] = pktrunc(pb[0], pb[1]);
        }
        PIN_V(A1.v); PIN_V(A2.v);
    }

    int sc = 0;                   // accumulated pow2 exponent (per column)
    f32x16 ZR;
    #pragma unroll
    for (int i = 0; i < 16; ++i) ZR[i] = 0.f;
    PIN_V(ZR);
    f32x16 C;

    #pragma unroll 4
    for (int t = tm; t < te; ++t) {
        // ---- step t: two chained MFMAs (K=32), operands pinned to VGPRs ----
        C = __builtin_amdgcn_mfma_f32_32x32x16_bf16(A1.v, B1f.v, ZR, 0, 0, 0);
        C = __builtin_amdgcn_mfma_f32_32x32x16_bf16(A2.v, B2f.v, C, 0, 0, 0);
        PIN_V(C);

        // ---- prefetch feat[t+4] (clamped; vector load, in-order vmcnt) ----
        const int tp = (t + 4 < te) ? (t + 4) : (te - 1);
        float fl = fb[(size_t)tp * LN + n];

        // ---- build A(t+1) from f1: independent of C, fills MFMA hazard ----
        float F = __expf(f1);
        f32x2 F2; F2[0] = F; F2[1] = F;
        #pragma unroll
        for (int r = 0; r < 4; ++r) {
            f32x2 pa = EA[r] * F2;
            f32x2 pb = EB[r] * F2;
            A1n.u[r] = pktrunc(pa[0], pa[1]);
            A2n.u[r] = pktrunc(pb[0], pb[1]);
        }
        PIN_V(A1n.v); PIN_V(A2n.v);

        // ---- per-column pow2 rescale every 16 steps (exact; diag commutes) ----
        if ((t & 15) == 15) {
            float cm = C[0];
            #pragma unroll
            for (int i = 1; i < 16; ++i) cm = fmaxf(cm, C[i]);
            unsigned ca = __float_as_uint(cm), cb = ca;
            PLSWAP(ca, cb);                       // column consensus across halves
            cm = fmaxf(__uint_as_float(ca), __uint_as_float(cb));
            cm = fmaxf(cm, 1e-30f);
            int ex; frexpf(cm, &ex);
            sc += ex;
            #pragma unroll
            for (int i = 0; i < 16; ++i) C[i] = ldexpf(C[i], -ex);
        }

        // ---- C (col=l&31, row=(r&3)+8*(r>>2)+4h) -> next-step B operands ----
        unsigned PK[8];
        #pragma unroll
        for (int r = 0; r < 8; ++r) PK[r] = pktrunc(C[2 * r], C[2 * r + 1]);
        PLSWAP(PK[0], PK[2]);  PLSWAP(PK[1], PK[3]);
        PLSWAP(PK[4], PK[6]);  PLSWAP(PK[5], PK[7]);
        B1f.u[0] = PK[0]; B1f.u[1] = PK[1]; B1f.u[2] = PK[2]; B1f.u[3] = PK[3];
        B2f.u[0] = PK[4]; B2f.u[1] = PK[5]; B2f.u[2] = PK[6]; B2f.u[3] = PK[7];
        PIN_V(B1f.v); PIN_V(B2f.v);

        // ---- rotate pipelines (unroll 4 makes these renames, not movs) ----
        A1 = A1n; A2 = A2n;
        f1 = f2; f2 = f3; f3 = fl;
    }

    // write log-space chunk matrix: log(true) = ln(C) + sc*ln2 + K*len
    const float add = KSHIFT * (float)(te - tm) + (float)sc * LN2F;
    float* __restrict__ w = ws + ((size_t)gid << 10);
    #pragma unroll
    for (int r = 0; r < 16; ++r) {
        int row = (r & 3) + 8 * (r >> 2) + 4 * h;
        float v = C[r];
        w[row * LN + n] = (v > 0.f) ? (__logf(v) + add) : -10000.0f;
    }
}

// ---------------- Phase 2: log-space combine + final lse ----------------
__global__ __launch_bounds__(64) void crf_combine(
    const float* __restrict__ trans,
    const float* __restrict__ feat,
    const float* __restrict__ ws,
    float* __restrict__ out,
    int CHS)
{
    const int CH = 1 << CHS;
    const int l = threadIdx.x & 63, i = l & 31;
    const int seq = blockIdx.x * 2 + (l >> 5);
    const int bb = (l & 32) << 2;   // group-local bpermute base

    // alpha_1[i] = trans[i][0] + feat[1][i]  (exact)
    float alpha = trans[i * LN] + feat[(size_t)seq * TN * LN + LN + i];
    const float* __restrict__ wsb = ws + ((size_t)seq << (10 + CHS));

    for (int c = 0; c < CH; ++c) {
        const float4* Mr = (const float4*)(wsb + (c << 10) + i * LN);
        float vv[32];
        #pragma unroll
        for (int q = 0; q < 8; ++q) {
            float4 m4 = Mr[q];
            vv[4 * q + 0] = m4.x; vv[4 * q + 1] = m4.y;
            vv[4 * q + 2] = m4.z; vv[4 * q + 3] = m4.w;
        }
        float mx = -1e30f;
        #pragma unroll
        for (int j = 0; j < 32; ++j) {
            int r = __builtin_amdgcn_ds_bpermute(bb + (j << 2), __float_as_int(alpha));
            vv[j] += __int_as_float(r);
            mx = fmaxf(mx, vv[j]);
        }
        float s = 0.f;
        #pragma unroll
        for (int j = 0; j < 32; ++j) s += __expf(vv[j] - mx);
        alpha = mx + __logf(s);
    }

    // forward score = lse over 32 states
    float m = alpha;
    #pragma unroll
    for (int s = 16; s; s >>= 1) m = fmaxf(m, __shfl_xor(m, s, 32));
    float es = __expf(alpha - m);
    #pragma unroll
    for (int s = 16; s; s >>= 1) es += __shfl_xor(es, s, 32);
    float fs = m + __logf(es);

    if (i == 0) atomicAdd(out, fs * (1.0f / (float)BN));
}

extern "C" void kernel_launch(void* const* d_in, const int* in_sizes, int n_in,
                              void* d_out, int out_size, void* d_ws, size_t ws_size,
                              hipStream_t stream) {
    const float* features    = (const float*)d_in[0];
    const float* transitions = (const float*)d_in[1];
    const int*   labels      = (const int*)d_in[2];
    float* out = (float*)d_out;
    float* ws  = (float*)d_ws;

    int CHS = 3;
    while (CHS > 0 && ws_size < (((size_t)BN << CHS) * (LN * LN * 4))) --CHS;
    const int CH = 1 << CHS;

    hipMemsetAsync(out, 0, sizeof(float), stream);
    crf_chunk<<<dim3((BN * CH) / 4), dim3(256), 0, stream>>>(
        features, transitions, labels, ws, out, CHS);
    crf_combine<<<dim3(BN / 2), dim3(64), 0, stream>>>(
        transitions, features, ws, out, CHS);
}

// Round 7
// 220.961 us; speedup vs baseline: 1.1208x; 1.0205x over previous
//
#include <hip/hip_runtime.h>
#include <hip/hip_bf16.h>

// CRF loss via associative chunked scan (MFMA layouts verified R2-R6).
// R7: inline-asm MFMA with explicit "v" tuple constraints (forces the whole
// MFMA web into arch VGPRs -- R3-R6 showed the compiler homes it in AGPRs and
// threads ~24 v_accvgpr moves/step through the serial chain). Hazard nops are
// carried inside the asm block (19 cyc >= 18 wait states for 16-pass MFMA ->
// VALU read). Each wave runs TWO independent chunks whose 4 MFMAs share one
// block: each chain's repack/A-build hides the other's latency.

constexpr int BN = 1024, TN = 1024, LN = 32;
constexpr float KSHIFT = 8.5f;     // per-step factors ~e^{-2}: monotone decay
constexpr float LN2F   = 0.69314718056f;

typedef __attribute__((ext_vector_type(8)))  short bf16x8;
typedef __attribute__((ext_vector_type(16))) float f32x16;
typedef __attribute__((ext_vector_type(2)))  float f32x2;

union BU { bf16x8 v; unsigned u[4]; };

// pack two f32 -> (bf16(a) | bf16(b)<<16) by truncation: one v_perm_b32
static __device__ __forceinline__ unsigned pktrunc(float a, float b) {
    return __builtin_amdgcn_perm(__float_as_uint(b), __float_as_uint(a), 0x07060302u);
}
// v_permlane32_swap_b32: a.row1 <-> b.row0 (register-only cross-half exchange)
#define PLSWAP(a, b) asm("v_permlane32_swap_b32 %0, %1" : "+v"(a), "+v"(b))

// ---------------- Phase 1: chunk transfer-matrix products ----------------
__global__ __launch_bounds__(256, 2) void crf_chunk(
    const float* __restrict__ feat,   // [B][T][L]
    const float* __restrict__ trans,  // [L][L]
    const int*   __restrict__ lab,    // [B][T]
    float* __restrict__ ws,           // [B*CH][32][32] log-space products
    float* __restrict__ out,          // [1] (gold subtracted here)
    int CHS)
{
    const int CH = 1 << CHS, LEN = TN >> CHS;
    const int l = threadIdx.x & 63, n = l & 31, h = l >> 5;
    const int wid = threadIdx.x >> 6;
    const int W  = blockIdx.x * 4 + wid;       // wave id; handles chunks 2W, 2W+1
    const int ca = 2 * W, cb = 2 * W + 1;
    const int ba = ca >> CHS, bb = cb >> CHS;
    const int ia = ca & (CH - 1), ib = cb & (CH - 1);
    const float* __restrict__ fA = feat + (size_t)ba * TN * LN;
    const float* __restrict__ fB = feat + (size_t)bb * TN * LN;

    const int sta = ia * LEN, stb = ib * LEN;
    const int ta0 = (ia == 0) ? 2 : sta;       // chunk 0 of a seq: t=1 folded into alpha_1
    const int tb0 = (ib == 0) ? 2 : stb;
    const int na  = sta + LEN - ta0;           // LEN or LEN-2
    const int nb  = stb + LEN - tb0;
    const int off = nb - na;                   // 0 or 2 (b never shorter than a)
    const int tea = sta + LEN, teb = stb + LEN;

    // ---- gold path: vectorized gather for both chunks (no in-loop scalars) ----
    {
        const int* __restrict__ lbA = lab + (size_t)ba * TN;
        const int* __restrict__ lbB = lab + (size_t)bb * TN;
        float gsum = 0.f;
        for (int r = 0; r < LEN; r += 64) {
            int t = sta + r + l;
            if (t >= 1) {
                int cur = lbA[t];
                gsum += trans[cur * LN + lbA[t - 1]] + fA[(size_t)t * LN + cur];
            }
        }
        for (int r = 0; r < LEN; r += 64) {
            int t = stb + r + l;
            if (t >= 1) {
                int cur = lbB[t];
                gsum += trans[cur * LN + lbB[t - 1]] + fB[(size_t)t * LN + cur];
            }
        }
        #pragma unroll
        for (int s = 32; s; s >>= 1) gsum += __shfl_xor(gsum, s, 64);
        if (l == 0) atomicAdd(out, -gsum * (1.0f / (float)BN));
    }

    // A-operand constants (shared by both chains): E pairs for k=8h+2r(+1), 16+8h+2r(+1)
    f32x2 EA[4], EB[4];
    #pragma unroll
    for (int r = 0; r < 4; ++r) {
        EA[r][0] = __expf(trans[n * LN + 8 * h + 2 * r]          - KSHIFT);
        EA[r][1] = __expf(trans[n * LN + 8 * h + 2 * r + 1]      - KSHIFT);
        EB[r][0] = __expf(trans[n * LN + 16 + 8 * h + 2 * r]     - KSHIFT);
        EB[r][1] = __expf(trans[n * LN + 16 + 8 * h + 2 * r + 1] - KSHIFT);
    }

    auto buildA = [&](float F, BU& A1, BU& A2) {
        f32x2 F2; F2[0] = F; F2[1] = F;
        #pragma unroll
        for (int r = 0; r < 4; ++r) {
            f32x2 pa = EA[r] * F2;
            f32x2 pb = EB[r] * F2;
            A1.u[r] = pktrunc(pa[0], pa[1]);
            A2.u[r] = pktrunc(pb[0], pb[1]);
        }
    };
    auto repack = [&](f32x16& C, BU& B1, BU& B2) {
        unsigned PK[8];
        #pragma unroll
        for (int r = 0; r < 8; ++r) PK[r] = pktrunc(C[2 * r], C[2 * r + 1]);
        PLSWAP(PK[0], PK[2]);  PLSWAP(PK[1], PK[3]);
        PLSWAP(PK[4], PK[6]);  PLSWAP(PK[5], PK[7]);
        B1.u[0] = PK[0]; B1.u[1] = PK[1]; B1.u[2] = PK[2]; B1.u[3] = PK[3];
        B2.u[0] = PK[4]; B2.u[1] = PK[5]; B2.u[2] = PK[6]; B2.u[3] = PK[7];
    };
    auto rescale = [&](f32x16& C, int& sc) {
        float cm = C[0];
        #pragma unroll
        for (int i = 1; i < 16; ++i) cm = fmaxf(cm, C[i]);
        unsigned x = __float_as_uint(cm), y = x;
        PLSWAP(x, y);                              // column consensus across halves
        cm = fmaxf(__uint_as_float(x), __uint_as_float(y));
        cm = fmaxf(cm, 1e-30f);
        int ex; frexpf(cm, &ex);
        sc += ex;
        #pragma unroll
        for (int i = 0; i < 16; ++i) C[i] = ldexpf(C[i], -ex);
    };

    // Running products as B operands (lane -> col n, k=8h+e); init Identity.
    BU B1a, B2a, B1b, B2b;
    #pragma unroll
    for (int r = 0; r < 4; ++r) {
        int k0 = 8 * h + 2 * r, k1 = k0 + 1;
        unsigned lo = (k0 == n ? 0x3F80u : 0u) | ((k1 == n ? 0x3F80u : 0u) << 16);
        unsigned hi = (k0 + 16 == n ? 0x3F80u : 0u) | ((k1 + 16 == n ? 0x3F80u : 0u) << 16);
        B1a.u[r] = lo; B2a.u[r] = hi; B1b.u[r] = lo; B2b.u[r] = hi;
    }

    f32x16 ZR;
    #pragma unroll
    for (int i = 0; i < 16; ++i) ZR[i] = 0.f;
    f32x16 Ca, Cb;

    // ---- feature pipelines (depth 4) + first A operands ----
    BU A1a, A2a, A1b, A2b;
    buildA(__expf(fA[(size_t)ta0 * LN + n]), A1a, A2a);
    buildA(__expf(fB[(size_t)tb0 * LN + n]), A1b, A2b);
    float fa1 = fA[(size_t)(ta0 + 1) * LN + n];
    float fa2 = fA[(size_t)(ta0 + 2) * LN + n];
    float fa3 = fA[(size_t)(ta0 + 3) * LN + n];
    float fb1 = fB[(size_t)(tb0 + 1) * LN + n];
    float fb2 = fB[(size_t)(tb0 + 2) * LN + n];
    float fb3 = fB[(size_t)(tb0 + 3) * LN + n];

    int sca = 0, scb = 0;

    // ---- solo prologue for chain b (off = 0 or 2 steps; wave-uniform) ----
    for (int k = 0; k < off; ++k) {
        asm volatile(
            "s_nop 1\n"
            "v_mfma_f32_32x32x16_bf16 %0, %1, %2, %5\n"
            "v_mfma_f32_32x32x16_bf16 %0, %3, %4, %0\n"
            "s_nop 7\n"
            "s_nop 7\n"
            "s_nop 2\n"
            : "=&v"(Cb)
            : "v"(A1b.v), "v"(B1b.v), "v"(A2b.v), "v"(B2b.v), "v"(ZR));
        int tp = tb0 + k + 4; tp = (tp < teb) ? tp : (teb - 1);
        float flb = fB[(size_t)tp * LN + n];
        buildA(__expf(fb1), A1b, A2b);
        repack(Cb, B1b, B2b);
        fb1 = fb2; fb2 = fb3; fb3 = flb;
    }

    // ---- joint main loop: one step of each chain per iteration ----
    for (int k = 0; k < na; ++k) {
        asm volatile(
            "s_nop 1\n"
            "v_mfma_f32_32x32x16_bf16 %0, %2, %3, %6\n"
            "v_mfma_f32_32x32x16_bf16 %1, %4, %5, %6\n"
            "v_mfma_f32_32x32x16_bf16 %0, %7, %8, %0\n"
            "v_mfma_f32_32x32x16_bf16 %1, %9, %10, %1\n"
            "s_nop 7\n"
            "s_nop 7\n"
            "s_nop 2\n"
            : "=&v"(Ca), "=&v"(Cb)
            : "v"(A1a.v), "v"(B1a.v), "v"(A1b.v), "v"(B1b.v), "v"(ZR),
              "v"(A2a.v), "v"(B2a.v), "v"(A2b.v), "v"(B2b.v));

        // prefetch step k+4 features for both chains (clamped)
        int tpa = ta0 + k + 4;       tpa = (tpa < tea) ? tpa : (tea - 1);
        int tpb = tb0 + off + k + 4; tpb = (tpb < teb) ? tpb : (teb - 1);
        float fla = fA[(size_t)tpa * LN + n];
        float flb = fB[(size_t)tpb * LN + n];

        // next-step A operands (independent of C: fills residual MFMA latency)
        buildA(__expf(fa1), A1a, A2a);
        buildA(__expf(fb1), A1b, A2b);

        // per-column pow2 rescale every 16 steps (exact; diag commutes right)
        if ((k & 15) == 15) { rescale(Ca, sca); rescale(Cb, scb); }

        // C -> next-step B operands (layout verified R2)
        repack(Ca, B1a, B2a);
        repack(Cb, B1b, B2b);

        fa1 = fa2; fa2 = fa3; fa3 = fla;
        fb1 = fb2; fb2 = fb3; fb3 = flb;
    }

    // ---- write log-space chunk matrices: log = ln(C) + sc*ln2 + K*steps ----
    const float adda = KSHIFT * (float)na + (float)sca * LN2F;
    const float addb = KSHIFT * (float)nb + (float)scb * LN2F;
    float* __restrict__ wa = ws + ((size_t)ca << 10);
    float* __restrict__ wb = ws + ((size_t)cb << 10);
    #pragma unroll
    for (int r = 0; r < 16; ++r) {
        int row = (r & 3) + 8 * (r >> 2) + 4 * h;
        float va = Ca[r], vb = Cb[r];
        wa[row * LN + n] = (va > 0.f) ? (__logf(va) + adda) : -10000.0f;
        wb[row * LN + n] = (vb > 0.f) ? (__logf(vb) + addb) : -10000.0f;
    }
}

// ---------------- Phase 2: log-space combine + final lse ----------------
__global__ __launch_bounds__(64) void crf_combine(
    const float* __restrict__ trans,
    const float* __restrict__ feat,
    const float* __restrict__ ws,
    float* __restrict__ out,
    int CHS)
{
    const int CH = 1 << CHS;
    const int l = threadIdx.x & 63, i = l & 31;
    const int seq = blockIdx.x * 2 + (l >> 5);
    const int bb = (l & 32) << 2;   // group-local bpermute base

    // alpha_1[i] = trans[i][0] + feat[1][i]  (exact)
    float alpha = trans[i * LN] + feat[(size_t)seq * TN * LN + LN + i];
    const float* __restrict__ wsb = ws + ((size_t)seq << (10 + CHS));

    for (int c = 0; c < CH; ++c) {
        const float4* Mr = (const float4*)(wsb + (c << 10) + i * LN);
        float vv[32];
        #pragma unroll
        for (int q = 0; q < 8; ++q) {
            float4 m4 = Mr[q];
            vv[4 * q + 0] = m4.x; vv[4 * q + 1] = m4.y;
            vv[4 * q + 2] = m4.z; vv[4 * q + 3] = m4.w;
        }
        float mx = -1e30f;
        #pragma unroll
        for (int j = 0; j < 32; ++j) {
            int r = __builtin_amdgcn_ds_bpermute(bb + (j << 2), __float_as_int(alpha));
            vv[j] += __int_as_float(r);
            mx = fmaxf(mx, vv[j]);
        }
        float s = 0.f;
        #pragma unroll
        for (int j = 0; j < 32; ++j) s += __expf(vv[j] - mx);
        alpha = mx + __logf(s);
    }

    // forward score = lse over 32 states
    float m = alpha;
    #pragma unroll
    for (int s = 16; s; s >>= 1) m = fmaxf(m, __shfl_xor(m, s, 32));
    float es = __expf(alpha - m);
    #pragma unroll
    for (int s = 16; s; s >>= 1) es += __shfl_xor(es, s, 32);
    float fs = m + __logf(es);

    if (i == 0) atomicAdd(out, fs * (1.0f / (float)BN));
}

extern "C" void kernel_launch(void* const* d_in, const int* in_sizes, int n_in,
                              void* d_out, int out_size, void* d_ws, size_t ws_size,
                              hipStream_t stream) {
    const float* features    = (const float*)d_in[0];
    const float* transitions = (const float*)d_in[1];
    const int*   labels      = (const int*)d_in[2];
    float* out = (float*)d_out;
    float* ws  = (float*)d_ws;

    int CHS = 3;
    while (CHS > 0 && ws_size < (((size_t)BN << CHS) * (LN * LN * 4))) --CHS;
    const int CH = 1 << CHS;

    hipMemsetAsync(out, 0, sizeof(float), stream);
    // 2 chunks per wave, 4 waves per block
    crf_chunk<<<dim3((BN * CH) / 8), dim3(256), 0, stream>>>(
        features, transitions, labels, ws, out, CHS);
    crf_combine<<<dim3(BN / 2), dim3(64), 0, stream>>>(
        transitions, features, ws, out, CHS);
}